// Round 4
// baseline (3060.862 us; speedup 1.0000x reference)
//
#include <hip/hip_runtime.h>

// ROI align (14x14 bilinear) + 2x2 maxpool -> 7x7. out (4,512,256,7,7) f32.
//
// R3 lesson: LDS staging round-trip (16 ds_write2 + 14 ds_read2 per row per
// wave) saturated the DS pipe (~55 us/CU of DS issue alone). Root cause: the
// (b,ch,row,col) layout forces staging for coalescing. Fix: repack features
// once into T[b][row][c0][ch] (channel-innermost) where each uint packs
// bf16(F[c0]) | bf16(F[c0+1])<<16 -- both bilinear neighbors in ONE 4B load,
// lanes(=channels) consecutive -> 256 B/instr coalesced, ZERO LDS in the
// main loop. bf16 halves L1 bytes (L1 is the new floor, ~17 us).
// Accuracy: bf16 feature rounding adds <= ~0.02 absmax vs 0.0994 threshold.

#define ROWU 12544            // 49*256 uints per (b,row) chunk of T

__global__ __launch_bounds__(256) void roi_transpose(
    const float* __restrict__ F,        // (4,256,50,50)
    unsigned int* __restrict__ T)       // (4,50,49,256) packed bf16 pairs
{
    const int bid = blockIdx.x;         // 800 = 4 b * 50 p * 4 chgroups
    const int b   = bid / 200;
    const int r   = bid % 200;
    const int p   = r >> 2;
    const int g   = r & 3;              // channel group of 64
    const int tid = threadIdx.x;

    __shared__ float sF[64][51];        // +1 pad

    {
        const int c   = tid & 63;       // col 0..49 active
        const int ch4 = tid >> 6;       // 0..3
        if (c < 50) {
            #pragma unroll
            for (int k = 0; k < 16; ++k) {
                const int chl = k * 4 + ch4;
                sF[chl][c] = F[(((size_t)(b * 256 + g * 64 + chl)) * 50 + p) * 50 + c];
            }
        }
    }
    __syncthreads();
    {
        const int chl = tid & 63;
        const int c0g = tid >> 6;       // 0..3
        unsigned int* Tp = T + (size_t)(b * 50 + p) * ROWU + g * 64 + chl;
        #pragma unroll
        for (int k = 0; k < 13; ++k) {
            const int c0 = c0g + 4 * k;
            if (c0 < 49) {
                unsigned int ua = __float_as_uint(sF[chl][c0]);
                ua = (ua + 0x7fffu + ((ua >> 16) & 1u)) >> 16;          // RNE bf16
                unsigned int ub = __float_as_uint(sF[chl][c0 + 1]);
                ub = (ub + 0x7fffu + ((ub >> 16) & 1u)) & 0xffff0000u;  // RNE, high
                Tp[c0 * 256] = ub | ua;
            }
        }
    }
}

__global__ __launch_bounds__(256, 3) void roi_main(
    const float* __restrict__ proposals,     // (4,512,4)
    const unsigned int* __restrict__ T,      // (4,50,49,256)
    float* __restrict__ out)                 // (4,512,256,7,7)
{
    const int bid  = blockIdx.x;             // b*512+n
    const int b    = bid >> 9;
    const int tid  = threadIdx.x;            // = channel 0..255
    const int wv   = tid >> 6;
    const int lane = tid & 63;

    __shared__ float sbuf[4][3136];          // 50176 B, epilogue only

    // ---- proposal -> box (numpy f32 semantics) ----
    const float4 prop = *(const float4*)(proposals + (size_t)bid * 4);
    const int x = (int)(prop.x * 0.0625f);
    const int y = (int)(prop.y * 0.0625f);
    const int w = (int)(prop.z * 0.0625f);   // 5..22
    const int h = (int)(prop.w * 0.0625f);   // 5..22

    // ---- uniform interp tables, computed redundantly per thread ----
    float cf[14]; int cidx[14]; int rls[14]; float rfs[14];
    const float csc = (float)(h - 1) / 13.0f;
    const float rsc = (float)(w - 1) / 13.0f;
    #pragma unroll
    for (int j = 0; j < 14; ++j) {
        const float c = (float)j * csc;
        const int lo  = (int)c;
        cidx[j] = __builtin_amdgcn_readfirstlane(lo * 256);
        cf[j]   = (lo + 1 > h - 1) ? 0.0f : (c - (float)lo);
        const float rc = (float)j * rsc;
        const int rlo  = (int)rc;
        rls[j] = __builtin_amdgcn_readfirstlane(rlo);
        rfs[j] = (rlo + 1 > w - 1) ? 0.0f : (rc - (float)rlo);
    }

    // thread's base into T: (b, row x, col-pair y, channel tid)
    const unsigned int* Tb = T + (size_t)(b * 50 + x) * ROWU + y * 256 + tid;

    unsigned int A[14], B_[14];
    float M0[14], M1[14], res[49];

    auto issue = [&](unsigned int* P, int p) {
        const unsigned int* rp = Tb + (size_t)p * ROWU;
        #pragma unroll
        for (int j = 0; j < 14; ++j) P[j] = rp[cidx[j]];
    };
    auto lerp = [&](const unsigned int* P, float* M) {
        #pragma unroll
        for (int j = 0; j < 14; ++j) {
            const float lo = __uint_as_float(P[j] << 16);
            const float hi = __uint_as_float(P[j] & 0xffff0000u);
            M[j] = lo + cf[j] * (hi - lo);   // cf==0 when col clamped
        }
    };
    auto emit = [&](int p) {
        #pragma unroll
        for (int i2 = 0; i2 < 14; ++i2) {
            if (rls[i2] == p - 1) {          // uniform (SGPR) guard
                const float rf = rfs[i2];
                #pragma unroll
                for (int q = 0; q < 7; ++q) {
                    const float a0 = M0[2*q]   + rf * (M1[2*q]   - M0[2*q]);
                    const float a1 = M0[2*q+1] + rf * (M1[2*q+1] - M0[2*q+1]);
                    const float m  = fmaxf(a0, a1);
                    const int  o   = (i2 >> 1) * 7 + q;   // compile-time
                    if (i2 & 1) res[o] = fmaxf(res[o], m);
                    else        res[o] = m;
                }
            }
        }
    };

    // ---- main loop: 2-deep register prefetch ping-pong, no LDS ----
    issue(A, 0);
    issue(B_, 1);                            // w >= 5 always
    lerp(A, M1);                             // row 0 (waits A only)

    int p = 1;
    for (;;) {
        #pragma unroll
        for (int j = 0; j < 14; ++j) M0[j] = M1[j];
        if (p < w) issue(A, p + 1);
        lerp(B_, M1);                        // row p
        emit(p);
        if (p == w) break;
        ++p;
        #pragma unroll
        for (int j = 0; j < 14; ++j) M0[j] = M1[j];
        if (p < w) issue(B_, p + 1);
        lerp(A, M1);                         // row p
        emit(p);
        if (p == w) break;
        ++p;
    }

    // ---- per-wave epilogue: regs -> LDS -> coalesced float4 stores ----
    float* wb = sbuf[wv];
    #pragma unroll
    for (int j = 0; j < 49; ++j)             // stride 49: 2-way alias = free
        wb[lane * 49 + j] = res[j];
    asm volatile("s_waitcnt lgkmcnt(0)" ::: "memory");  // cross-lane visibility
    const float4* sv = (const float4*)wb;               // 784 float4s
    float4* ov = (float4*)(out + (size_t)bid * 12544) + wv * 784;
    #pragma unroll
    for (int k = 0; k < 13; ++k) {
        const int idx = k * 64 + lane;
        if (idx < 784) ov[idx] = sv[idx];
    }
}

extern "C" void kernel_launch(void* const* d_in, const int* in_sizes, int n_in,
                              void* d_out, int out_size, void* d_ws, size_t ws_size,
                              hipStream_t stream) {
    const float* proposals = (const float*)d_in[0];   // (4,512,4)
    const float* features  = (const float*)d_in[1];   // (4,256,50,50)
    float* outp = (float*)d_out;
    unsigned int* T = (unsigned int*)d_ws;            // needs 10.04 MB

    roi_transpose<<<dim3(800), dim3(256), 0, stream>>>(features, T);
    roi_main<<<dim3(2048), dim3(256), 0, stream>>>(proposals, T, outp);
}

// Round 5
// 153.386 us; speedup vs baseline: 19.9553x; 19.9553x over previous
//
#include <hip/hip_runtime.h>

// ROI align (14x14 bilinear) + 2x2 maxpool -> 7x7. out (4,512,256,7,7) f32.
//
// Design (R4, validated): repack features once into T[b][row][c0][ch],
// channel-innermost, each uint = bf16(F[c0]) | bf16(F[c0+1])<<16 -- both
// bilinear col-neighbors in ONE 4B load, lanes(=channels) consecutive ->
// 256 B/instr coalesced, ZERO LDS in the main loop.
//
// R4 lesson (3060 us, 11 GB HBM): passing register arrays through lambda
// POINTER PARAMETERS (lerp(A)/lerp(B)) creates a pointer-phi -> SROA fails
// -> every array lives in scratch. Fix: dedicated issueA/issueB/lerpA/lerpB
// closures, each hard-wired to its own array; ping-pong via uniform p&1
// branch; ALL array indices compile-time. launch_bounds (256,2) gives the
// allocator 256 VGPRs of headroom.

#define ROWU 12544            // 49*256 uints per (b,row) chunk of T

__global__ __launch_bounds__(256) void roi_transpose(
    const float* __restrict__ F,        // (4,256,50,50)
    unsigned int* __restrict__ T)       // (4,50,49,256) packed bf16 pairs
{
    const int bid = blockIdx.x;         // 800 = 4 b * 50 p * 4 chgroups
    const int b   = bid / 200;
    const int r   = bid % 200;
    const int p   = r >> 2;
    const int g   = r & 3;              // channel group of 64
    const int tid = threadIdx.x;

    __shared__ float sF[64][51];        // +1 pad

    {
        const int c   = tid & 63;       // col 0..49 active
        const int ch4 = tid >> 6;       // 0..3
        if (c < 50) {
            #pragma unroll
            for (int k = 0; k < 16; ++k) {
                const int chl = k * 4 + ch4;
                sF[chl][c] = F[(((size_t)(b * 256 + g * 64 + chl)) * 50 + p) * 50 + c];
            }
        }
    }
    __syncthreads();
    {
        const int chl = tid & 63;
        const int c0g = tid >> 6;       // 0..3
        unsigned int* Tp = T + (size_t)(b * 50 + p) * ROWU + g * 64 + chl;
        #pragma unroll
        for (int k = 0; k < 13; ++k) {
            const int c0 = c0g + 4 * k;
            if (c0 < 49) {
                unsigned int ua = __float_as_uint(sF[chl][c0]);
                ua = (ua + 0x7fffu + ((ua >> 16) & 1u)) >> 16;          // RNE bf16
                unsigned int ub = __float_as_uint(sF[chl][c0 + 1]);
                ub = (ub + 0x7fffu + ((ub >> 16) & 1u)) & 0xffff0000u;  // RNE, high
                Tp[c0 * 256] = ub | ua;
            }
        }
    }
}

__global__ __launch_bounds__(256, 2) void roi_main(
    const float* __restrict__ proposals,     // (4,512,4)
    const unsigned int* __restrict__ T,      // (4,50,49,256)
    float* __restrict__ out)                 // (4,512,256,7,7)
{
    const int bid  = blockIdx.x;             // b*512+n
    const int b    = bid >> 9;
    const int tid  = threadIdx.x;            // = channel 0..255
    const int wv   = tid >> 6;
    const int lane = tid & 63;

    __shared__ float sbuf[4][3136];          // 50176 B, epilogue only

    // ---- proposal -> box (numpy f32 semantics) ----
    const float4 prop = *(const float4*)(proposals + (size_t)bid * 4);
    const int x = (int)(prop.x * 0.0625f);
    const int y = (int)(prop.y * 0.0625f);
    const int w = (int)(prop.z * 0.0625f);   // 5..22
    const int h = (int)(prop.w * 0.0625f);   // 5..22

    // ---- uniform interp tables (redundant per thread; uniforms -> SGPR) ----
    float cf[14]; int cidx[14]; int rls[14]; float rfs[14];
    const float csc = (float)(h - 1) / 13.0f;
    const float rsc = (float)(w - 1) / 13.0f;
    #pragma unroll
    for (int j = 0; j < 14; ++j) {
        const float c = (float)j * csc;
        const int lo  = (int)c;
        cidx[j] = __builtin_amdgcn_readfirstlane(lo * 256);
        cf[j]   = (lo + 1 > h - 1) ? 0.0f : (c - (float)lo);
        const float rc = (float)j * rsc;
        const int rlo  = (int)rc;
        rls[j] = __builtin_amdgcn_readfirstlane(rlo);
        rfs[j] = (rlo + 1 > w - 1) ? 0.0f : (rc - (float)rlo);
    }

    // thread's base into T: (b, row x, col-pair y, channel tid)
    const unsigned int* Tb = T + (size_t)(b * 50 + x) * ROWU + y * 256 + tid;

    unsigned int A[14], B_[14];
    float M0[14], M1[14], res[49];

    // Each closure hard-references exactly one buffer: no pointer params,
    // no address escape, all indices compile-time -> SROA-safe.
    auto issueA = [&](int p) {
        const unsigned int* rp = Tb + (size_t)p * ROWU;
        #pragma unroll
        for (int j = 0; j < 14; ++j) A[j] = rp[cidx[j]];
    };
    auto issueB = [&](int p) {
        const unsigned int* rp = Tb + (size_t)p * ROWU;
        #pragma unroll
        for (int j = 0; j < 14; ++j) B_[j] = rp[cidx[j]];
    };
    auto lerpA = [&]() {
        #pragma unroll
        for (int j = 0; j < 14; ++j) {
            const float lo = __uint_as_float(A[j] << 16);
            const float hi = __uint_as_float(A[j] & 0xffff0000u);
            M1[j] = lo + cf[j] * (hi - lo);  // cf==0 when col clamped
        }
    };
    auto lerpB = [&]() {
        #pragma unroll
        for (int j = 0; j < 14; ++j) {
            const float lo = __uint_as_float(B_[j] << 16);
            const float hi = __uint_as_float(B_[j] & 0xffff0000u);
            M1[j] = lo + cf[j] * (hi - lo);
        }
    };
    auto emit = [&](int p) {
        #pragma unroll
        for (int i2 = 0; i2 < 14; ++i2) {
            if (rls[i2] == p - 1) {          // uniform (SGPR) guard
                const float rf = rfs[i2];
                #pragma unroll
                for (int q = 0; q < 7; ++q) {
                    const float a0 = M0[2*q]   + rf * (M1[2*q]   - M0[2*q]);
                    const float a1 = M0[2*q+1] + rf * (M1[2*q+1] - M0[2*q+1]);
                    const float m  = fmaxf(a0, a1);
                    const int  o   = (i2 >> 1) * 7 + q;   // compile-time
                    if (i2 & 1) res[o] = fmaxf(res[o], m);
                    else        res[o] = m;
                }
            }
        }
    };

    // ---- main loop: 2-deep prefetch, ping-pong via uniform parity ----
    issueA(0);
    issueB(1);                               // w >= 5 always
    lerpA();                                 // M1 = row 0 (waits A only)

    for (int p = 1; p <= w; ++p) {
        #pragma unroll
        for (int j = 0; j < 14; ++j) M0[j] = M1[j];
        if (p & 1) {                         // row p sits in B_
            if (p < w) issueA(p + 1);
            lerpB();
        } else {                             // row p sits in A
            if (p < w) issueB(p + 1);
            lerpA();
        }
        emit(p);
    }

    // ---- per-wave epilogue: regs -> LDS -> coalesced float4 stores ----
    float* wb = sbuf[wv];
    #pragma unroll
    for (int j = 0; j < 49; ++j)             // stride 49: 2-way alias = free
        wb[lane * 49 + j] = res[j];
    asm volatile("s_waitcnt lgkmcnt(0)" ::: "memory");  // cross-lane visibility
    const float4* sv = (const float4*)wb;               // 784 float4s
    float4* ov = (float4*)(out + (size_t)bid * 12544) + wv * 784;
    #pragma unroll
    for (int k = 0; k < 13; ++k) {
        const int idx = k * 64 + lane;
        if (idx < 784) ov[idx] = sv[idx];
    }
}

extern "C" void kernel_launch(void* const* d_in, const int* in_sizes, int n_in,
                              void* d_out, int out_size, void* d_ws, size_t ws_size,
                              hipStream_t stream) {
    const float* proposals = (const float*)d_in[0];   // (4,512,4)
    const float* features  = (const float*)d_in[1];   // (4,256,50,50)
    float* outp = (float*)d_out;
    unsigned int* T = (unsigned int*)d_ws;            // needs 10.04 MB

    roi_transpose<<<dim3(800), dim3(256), 0, stream>>>(features, T);
    roi_main<<<dim3(2048), dim3(256), 0, stream>>>(proposals, T, outp);
}